// Round 4
// baseline (152.921 us; speedup 1.0000x reference)
//
#include <hip/hip_runtime.h>

#define THRESH 1.0f
#define DECAY  0.5f

typedef float f32x4 __attribute__((ext_vector_type(4)));

constexpr int NPI = 4;  // neurons per inner iteration (8x dwordx4 loads in flight)

__global__ __launch_bounds__(256) void lif_kernel(const float* __restrict__ X,
                                                  float* __restrict__ S,
                                                  long long n_groups) {
    // one group = NPI consecutive neurons = NPI*2 float4s
    long long idx    = (long long)blockIdx.x * blockDim.x + threadIdx.x;
    long long stride = (long long)gridDim.x * blockDim.x;
    const f32x4* __restrict__ Xv = reinterpret_cast<const f32x4*>(X);
    f32x4* __restrict__ Sv = reinterpret_cast<f32x4*>(S);

    for (long long g = idx; g < n_groups; g += stride) {
        long long base = g * (NPI * 2);
        f32x4 v[NPI * 2];
        // Issue all loads back-to-back: 8 dwordx4 in flight per wave.
#pragma unroll
        for (int k = 0; k < NPI * 2; ++k) v[k] = Xv[base + k];

        f32x4 o[NPI * 2];
#pragma unroll
        for (int n = 0; n < NPI; ++n) {
            float xv[8] = {v[2*n][0], v[2*n][1], v[2*n][2], v[2*n][3],
                           v[2*n+1][0], v[2*n+1][1], v[2*n+1][2], v[2*n+1][3]};
            float sv[8];
            float mem = 0.0f;
#pragma unroll
            for (int t = 0; t < 8; ++t) {
                mem = mem * DECAY + xv[t];
                bool fired = (mem >= THRESH);
                sv[t] = fired ? 1.0f : 0.0f;
                mem   = fired ? 0.0f : mem;   // v_cndmask
            }
            o[2*n]   = (f32x4){sv[0], sv[1], sv[2], sv[3]};
            o[2*n+1] = (f32x4){sv[4], sv[5], sv[6], sv[7]};
        }
#pragma unroll
        for (int k = 0; k < NPI * 2; ++k) Sv[base + k] = o[k];
    }
}

__global__ __launch_bounds__(256) void lif_tail_kernel(const float* __restrict__ X,
                                                       float* __restrict__ S,
                                                       long long start_neuron,
                                                       long long n_neurons) {
    long long i = start_neuron + blockIdx.x * blockDim.x + threadIdx.x;
    if (i >= n_neurons) return;
    const f32x4* __restrict__ xp = reinterpret_cast<const f32x4*>(X + i * 8);
    f32x4 x0 = xp[0], x1 = xp[1];
    float xv[8] = {x0[0], x0[1], x0[2], x0[3], x1[0], x1[1], x1[2], x1[3]};
    float sv[8];
    float mem = 0.0f;
#pragma unroll
    for (int t = 0; t < 8; ++t) {
        mem = mem * DECAY + xv[t];
        bool fired = (mem >= THRESH);
        sv[t] = fired ? 1.0f : 0.0f;
        mem   = fired ? 0.0f : mem;
    }
    f32x4* __restrict__ op = reinterpret_cast<f32x4*>(S + i * 8);
    op[0] = (f32x4){sv[0], sv[1], sv[2], sv[3]};
    op[1] = (f32x4){sv[4], sv[5], sv[6], sv[7]};
}

extern "C" void kernel_launch(void* const* d_in, const int* in_sizes, int n_in,
                              void* d_out, int out_size, void* d_ws, size_t ws_size,
                              hipStream_t stream) {
    const float* X = (const float*)d_in[0];
    float* S = (float*)d_out;
    long long n_elems   = (long long)in_sizes[0];
    long long n_neurons = n_elems / 8;        // T = 8, last (contiguous) axis
    long long n_groups  = n_neurons / NPI;    // full groups of NPI neurons

    const int block = 256;
    long long want_blocks = (n_groups + block - 1) / block;
    int grid = (int)(want_blocks < 2048 ? want_blocks : 2048);
    if (grid > 0)
        lif_kernel<<<grid, block, 0, stream>>>(X, S, n_groups);

    long long tail_start = n_groups * NPI;
    long long tail = n_neurons - tail_start;   // 0 for this shape
    if (tail > 0) {
        int tgrid = (int)((tail + block - 1) / block);
        lif_tail_kernel<<<tgrid, block, 0, stream>>>(X, S, tail_start, n_neurons);
    }
}

// Round 5
// 108.764 us; speedup vs baseline: 1.4060x; 1.4060x over previous
//
#include <hip/hip_runtime.h>

#define THRESH 1.0f
#define DECAY  0.5f

typedef float f32x4 __attribute__((ext_vector_type(4)));

constexpr int NPI = 4;  // neurons per thread, taken from 4 distant chunks

__global__ __launch_bounds__(256) void lif_kernel(const float* __restrict__ X,
                                                  float* __restrict__ S,
                                                  long long chunk) {
    long long t = (long long)blockIdx.x * blockDim.x + threadIdx.x;
    if (t >= chunk) return;
    const f32x4* __restrict__ Xv = reinterpret_cast<const f32x4*>(X);
    f32x4* __restrict__ Sv = reinterpret_cast<f32x4*>(S);

    // 8 independent dwordx4 loads in flight; each instruction's lane-stride is
    // 32 B (consecutive threads -> consecutive neurons within a chunk).
    f32x4 v[NPI * 2];
#pragma unroll
    for (int n = 0; n < NPI; ++n) {
        long long nb = ((long long)n * chunk + t) * 2;
        v[2 * n]     = Xv[nb];
        v[2 * n + 1] = Xv[nb + 1];
    }

    f32x4 o[NPI * 2];
#pragma unroll
    for (int n = 0; n < NPI; ++n) {
        float xv[8] = {v[2*n][0], v[2*n][1], v[2*n][2], v[2*n][3],
                       v[2*n+1][0], v[2*n+1][1], v[2*n+1][2], v[2*n+1][3]};
        float sv[8];
        float mem = 0.0f;
#pragma unroll
        for (int tt = 0; tt < 8; ++tt) {
            mem = mem * DECAY + xv[tt];
            bool fired = (mem >= THRESH);
            sv[tt] = fired ? 1.0f : 0.0f;
            mem    = fired ? 0.0f : mem;   // v_cndmask
        }
        o[2*n]   = (f32x4){sv[0], sv[1], sv[2], sv[3]};
        o[2*n+1] = (f32x4){sv[4], sv[5], sv[6], sv[7]};
    }

#pragma unroll
    for (int n = 0; n < NPI; ++n) {
        long long nb = ((long long)n * chunk + t) * 2;
        Sv[nb]     = o[2 * n];
        Sv[nb + 1] = o[2 * n + 1];
    }
}

__global__ __launch_bounds__(256) void lif_tail_kernel(const float* __restrict__ X,
                                                       float* __restrict__ S,
                                                       long long start_neuron,
                                                       long long n_neurons) {
    long long i = start_neuron + (long long)blockIdx.x * blockDim.x + threadIdx.x;
    if (i >= n_neurons) return;
    const f32x4* __restrict__ xp = reinterpret_cast<const f32x4*>(X + i * 8);
    f32x4 x0 = xp[0], x1 = xp[1];
    float xv[8] = {x0[0], x0[1], x0[2], x0[3], x1[0], x1[1], x1[2], x1[3]};
    float sv[8];
    float mem = 0.0f;
#pragma unroll
    for (int t = 0; t < 8; ++t) {
        mem = mem * DECAY + xv[t];
        bool fired = (mem >= THRESH);
        sv[t] = fired ? 1.0f : 0.0f;
        mem   = fired ? 0.0f : mem;
    }
    f32x4* __restrict__ op = reinterpret_cast<f32x4*>(S + i * 8);
    op[0] = (f32x4){sv[0], sv[1], sv[2], sv[3]};
    op[1] = (f32x4){sv[4], sv[5], sv[6], sv[7]};
}

extern "C" void kernel_launch(void* const* d_in, const int* in_sizes, int n_in,
                              void* d_out, int out_size, void* d_ws, size_t ws_size,
                              hipStream_t stream) {
    const float* X = (const float*)d_in[0];
    float* S = (float*)d_out;
    long long n_elems   = (long long)in_sizes[0];
    long long n_neurons = n_elems / 8;          // T = 8, last (contiguous) axis
    long long chunk     = n_neurons / NPI;      // distant-chunk size

    const int block = 256;
    if (chunk > 0) {
        int grid = (int)((chunk + block - 1) / block);   // exact grid, no loop
        lif_kernel<<<grid, block, 0, stream>>>(X, S, chunk);
    }

    long long tail_start = chunk * NPI;
    long long tail = n_neurons - tail_start;    // 0 for this shape
    if (tail > 0) {
        int tgrid = (int)((tail + block - 1) / block);
        lif_tail_kernel<<<tgrid, block, 0, stream>>>(X, S, tail_start, n_neurons);
    }
}

// Round 6
// 83.223 us; speedup vs baseline: 1.8375x; 1.3069x over previous
//
#include <hip/hip_runtime.h>

#define THRESH 1.0f
#define DECAY  0.5f

typedef float f32x4 __attribute__((ext_vector_type(4)));

constexpr int BLOCK = 256;
constexpr int NEUR_PER_THREAD = 2;
constexpr int TILE_NEURONS = BLOCK * NEUR_PER_THREAD;   // 512 neurons / tile
constexpr int PAD = 12;                                 // floats per neuron in LDS (48 B, 16B-aligned)

__global__ __launch_bounds__(BLOCK) void lif_kernel(const float* __restrict__ X,
                                                    float* __restrict__ S,
                                                    long long n_neurons) {
    __shared__ float lds[TILE_NEURONS * PAD];           // 24 KiB
    const int tid = threadIdx.x;
    const long long total_f4 = n_neurons * 2;           // 2 float4 per neuron
    const long long n_tiles = (n_neurons + TILE_NEURONS - 1) / TILE_NEURONS;

    const f32x4* __restrict__ Xv = reinterpret_cast<const f32x4*>(X);
    f32x4* __restrict__ Sv = reinterpret_cast<f32x4*>(S);

    for (long long tile = blockIdx.x; tile < n_tiles; tile += gridDim.x) {
        const long long base_f4 = tile * (long long)TILE_NEURONS * 2;

        // Phase 1: contiguous global -> padded LDS.
        // PLAIN loads: X allocates in L2/L3 and stays resident across replays.
#pragma unroll
        for (int k = 0; k < 4; ++k) {
            int g = tid + k * BLOCK;                    // 0..1023 float4s in tile
            long long gi = base_f4 + g;
            if (gi < total_f4) {
                f32x4 v = Xv[gi];
                int neuron = g >> 1;
                int e4 = (g & 1) * 4;
                *reinterpret_cast<f32x4*>(&lds[neuron * PAD + e4]) = v;
            }
        }
        __syncthreads();

        // Phase 2: per-neuron recurrence in registers, spikes written back in place
#pragma unroll
        for (int r = 0; r < NEUR_PER_THREAD; ++r) {
            int ln = tid + r * BLOCK;                   // local neuron 0..511
            long long gn = tile * (long long)TILE_NEURONS + ln;
            if (gn < n_neurons) {
                f32x4 a = *reinterpret_cast<const f32x4*>(&lds[ln * PAD + 0]);
                f32x4 b = *reinterpret_cast<const f32x4*>(&lds[ln * PAD + 4]);
                float xv[8] = {a[0], a[1], a[2], a[3], b[0], b[1], b[2], b[3]};
                float sv[8];
                float mem = 0.0f;
#pragma unroll
                for (int t = 0; t < 8; ++t) {
                    mem = mem * DECAY + xv[t];
                    bool fired = (mem >= THRESH);
                    sv[t] = fired ? 1.0f : 0.0f;
                    mem   = fired ? 0.0f : mem;
                }
                f32x4 s0 = {sv[0], sv[1], sv[2], sv[3]};
                f32x4 s1 = {sv[4], sv[5], sv[6], sv[7]};
                *reinterpret_cast<f32x4*>(&lds[ln * PAD + 0]) = s0;
                *reinterpret_cast<f32x4*>(&lds[ln * PAD + 4]) = s1;
            }
        }
        __syncthreads();

        // Phase 3: padded LDS -> contiguous global.
        // NT stores on a fully lane-contiguous pattern: whole 64B lines per
        // wave instruction -> no partial-line amplification, and the write
        // stream does not evict X from the Infinity Cache between replays.
#pragma unroll
        for (int k = 0; k < 4; ++k) {
            int g = tid + k * BLOCK;
            long long gi = base_f4 + g;
            if (gi < total_f4) {
                int neuron = g >> 1;
                int e4 = (g & 1) * 4;
                f32x4 s = *reinterpret_cast<const f32x4*>(&lds[neuron * PAD + e4]);
                __builtin_nontemporal_store(s, &Sv[gi]);
            }
        }
        __syncthreads();   // protect LDS reuse across grid-stride iterations
    }
}

extern "C" void kernel_launch(void* const* d_in, const int* in_sizes, int n_in,
                              void* d_out, int out_size, void* d_ws, size_t ws_size,
                              hipStream_t stream) {
    const float* X = (const float*)d_in[0];
    float* S = (float*)d_out;
    long long n_elems   = (long long)in_sizes[0];
    long long n_neurons = n_elems / 8;   // T = 8, last (contiguous) axis

    const int block = BLOCK;
    long long n_tiles = (n_neurons + TILE_NEURONS - 1) / TILE_NEURONS;
    int grid = (int)(n_tiles < 2048 ? n_tiles : 2048);

    lif_kernel<<<grid, block, 0, stream>>>(X, S, n_neurons);
}

// Round 7
// 80.505 us; speedup vs baseline: 1.8995x; 1.0338x over previous
//
#include <hip/hip_runtime.h>

#define THRESH 1.0f
#define DECAY  0.5f

typedef float f32x4 __attribute__((ext_vector_type(4)));

constexpr int BLOCK = 256;
constexpr int NEUR_PER_THREAD = 2;
constexpr int TILE_NEURONS = BLOCK * NEUR_PER_THREAD;   // 512 neurons / tile
constexpr int PAD = 12;                                 // floats per neuron in LDS (48 B, 16B-aligned, 0 conflicts measured)

__global__ __launch_bounds__(BLOCK) void lif_kernel(const float* __restrict__ X,
                                                    float* __restrict__ S,
                                                    long long n_neurons) {
    __shared__ float lds[TILE_NEURONS * PAD];           // 24 KiB -> 6 blocks/CU
    const int tid = threadIdx.x;
    const long long tile = blockIdx.x;                  // exact grid: one tile per block
    const long long base_neuron = tile * TILE_NEURONS;
    const long long base_f4 = base_neuron * 2;
    const long long total_f4 = n_neurons * 2;

    const f32x4* __restrict__ Xv = reinterpret_cast<const f32x4*>(X);
    f32x4* __restrict__ Sv = reinterpret_cast<f32x4*>(S);

    // Phase 1: strided register loads (32B lane-stride, proven perf-neutral),
    // compute recurrence, write ONLY spikes into LDS (transposed layout).
#pragma unroll
    for (int r = 0; r < NEUR_PER_THREAD; ++r) {
        int ln = tid + r * BLOCK;                       // local neuron 0..511
        long long gn = base_neuron + ln;
        if (gn < n_neurons) {
            f32x4 a = Xv[gn * 2];                       // plain loads: keep X L3-resident
            f32x4 b = Xv[gn * 2 + 1];
            float xv[8] = {a[0], a[1], a[2], a[3], b[0], b[1], b[2], b[3]};
            float sv[8];
            float mem = 0.0f;
#pragma unroll
            for (int t = 0; t < 8; ++t) {
                mem = mem * DECAY + xv[t];
                bool fired = (mem >= THRESH);
                sv[t] = fired ? 1.0f : 0.0f;
                mem   = fired ? 0.0f : mem;             // v_cndmask
            }
            *reinterpret_cast<f32x4*>(&lds[ln * PAD + 0]) = (f32x4){sv[0], sv[1], sv[2], sv[3]};
            *reinterpret_cast<f32x4*>(&lds[ln * PAD + 4]) = (f32x4){sv[4], sv[5], sv[6], sv[7]};
        }
    }
    __syncthreads();                                    // the ONLY barrier

    // Phase 2: lane-contiguous NT stores — whole cachelines per wave
    // instruction (no partial-line amplification), bypassing L3 so the
    // write stream doesn't evict X between graph replays.
#pragma unroll
    for (int k = 0; k < 4; ++k) {
        int g = tid + k * BLOCK;                        // 0..1023 float4s in tile
        long long gi = base_f4 + g;
        if (gi < total_f4) {
            int neuron = g >> 1;
            int e4 = (g & 1) * 4;
            f32x4 s = *reinterpret_cast<const f32x4*>(&lds[neuron * PAD + e4]);
            __builtin_nontemporal_store(s, &Sv[gi]);
        }
    }
}

extern "C" void kernel_launch(void* const* d_in, const int* in_sizes, int n_in,
                              void* d_out, int out_size, void* d_ws, size_t ws_size,
                              hipStream_t stream) {
    const float* X = (const float*)d_in[0];
    float* S = (float*)d_out;
    long long n_elems   = (long long)in_sizes[0];
    long long n_neurons = n_elems / 8;   // T = 8, last (contiguous) axis

    long long n_tiles = (n_neurons + TILE_NEURONS - 1) / TILE_NEURONS;  // exact grid
    lif_kernel<<<(int)n_tiles, BLOCK, 0, stream>>>(X, S, n_neurons);
}